// Round 1
// baseline (536.179 us; speedup 1.0000x reference)
//
#include <hip/hip_runtime.h>

// Accumulator slots at the head of d_ws (floats):
//   [0] noise_sum   sum of beta where pid == 0
//   [1] nb          count of pid == 0 hits
//   [2] attr_sum    sum over valid pids>0 of (1 - max_beta)
//   [3] n_valid     count of valid pids>0
// Then: unsigned int max_bits[P] at ws+16.
//   max_bits[p] = __float_as_uint(max beta for p) + 1; 0 == "pid absent".
//   Valid because beta >= 0 (uniform [0,1)): nonneg-float bit patterns are
//   monotone under unsigned compare, and +1 cannot overflow (beta < 1.0
//   => bits <= 0x3F7FFFFF). Avoids a separate counts[] array/atomic.

#define ACC_NOISE  0
#define ACC_NB     1
#define ACC_ATTR   2
#define ACC_NVALID 3

__global__ void bg_init(float* __restrict__ acc,
                        unsigned int* __restrict__ max_bits,
                        const int* __restrict__ num_pids_p) {
    const int P = *num_pids_p;
    const int stride = gridDim.x * blockDim.x;
    int tid = blockIdx.x * blockDim.x + threadIdx.x;
    if (tid < 4) acc[tid] = 0.0f;
    for (int i = tid; i < P; i += stride) max_bits[i] = 0u;
}

__device__ __forceinline__ void bg_process(int p, float b,
                                           float& noise_local, int& nb_local,
                                           unsigned int* max_bits) {
    if (p == 0) {
        noise_local += b;
        nb_local += 1;
    } else {
        atomicMax(&max_bits[p], __float_as_uint(b) + 1u);
    }
}

__global__ void bg_main(const float* __restrict__ beta,
                        const int* __restrict__ pid,
                        float* __restrict__ acc,
                        unsigned int* __restrict__ max_bits,
                        int n) {
    const int stride = gridDim.x * blockDim.x;
    const int tid = blockIdx.x * blockDim.x + threadIdx.x;
    const int n4 = n >> 2;

    float noise_local = 0.0f;
    int nb_local = 0;

    const float4* __restrict__ b4 = (const float4*)beta;
    const int4* __restrict__ p4 = (const int4*)pid;
    for (int i = tid; i < n4; i += stride) {
        float4 b = b4[i];
        int4 p = p4[i];
        bg_process(p.x, b.x, noise_local, nb_local, max_bits);
        bg_process(p.y, b.y, noise_local, nb_local, max_bits);
        bg_process(p.z, b.z, noise_local, nb_local, max_bits);
        bg_process(p.w, b.w, noise_local, nb_local, max_bits);
    }
    // tail (n not divisible by 4)
    for (int i = (n4 << 2) + tid; i < n; i += stride) {
        bg_process(pid[i], beta[i], noise_local, nb_local, max_bits);
    }

    // wave-64 reduction of the (rare) noise contributions
    #pragma unroll
    for (int off = 32; off > 0; off >>= 1) {
        noise_local += __shfl_down(noise_local, off);
        nb_local    += __shfl_down(nb_local, off);
    }
    if ((threadIdx.x & 63) == 0 && nb_local != 0) {
        atomicAdd(&acc[ACC_NOISE], noise_local);
        atomicAdd(&acc[ACC_NB], (float)nb_local);
    }
}

__global__ void bg_reduce(const unsigned int* __restrict__ max_bits,
                          float* __restrict__ acc,
                          const int* __restrict__ num_pids_p) {
    const int P = *num_pids_p;
    const int stride = gridDim.x * blockDim.x;
    float s = 0.0f;
    int c = 0;
    for (int i = blockIdx.x * blockDim.x + threadIdx.x; i < P; i += stride) {
        if (i == 0) continue;  // pid 0 is noise, excluded from attractive term
        unsigned int v = max_bits[i];
        if (v != 0u) {
            s += 1.0f - __uint_as_float(v - 1u);
            c += 1;
        }
    }
    #pragma unroll
    for (int off = 32; off > 0; off >>= 1) {
        s += __shfl_down(s, off);
        c += __shfl_down(c, off);
    }
    if ((threadIdx.x & 63) == 0 && (c != 0 || s != 0.0f)) {
        atomicAdd(&acc[ACC_ATTR], s);
        atomicAdd(&acc[ACC_NVALID], (float)c);
    }
}

__global__ void bg_finalize(const float* __restrict__ acc,
                            float* __restrict__ out) {
    float nb = acc[ACC_NB];
    float n_valid = fmaxf(acc[ACC_NVALID], 1.0f);
    float attractive = acc[ACC_ATTR] / n_valid;
    float noise = 0.1f * acc[ACC_NOISE] / fmaxf(nb, 1.0f);
    out[0] = (nb == 0.0f) ? 0.0f : (attractive + noise);
}

extern "C" void kernel_launch(void* const* d_in, const int* in_sizes, int n_in,
                              void* d_out, int out_size, void* d_ws, size_t ws_size,
                              hipStream_t stream) {
    // inputs: 0=w, 1=beta, 2=x, 3=y, 4=particle_id, 5=num_pids (device scalar)
    const float* beta = (const float*)d_in[1];
    const int* pid = (const int*)d_in[4];
    const int* num_pids_p = (const int*)d_in[5];
    const int n = in_sizes[1];

    float* acc = (float*)d_ws;
    unsigned int* max_bits = (unsigned int*)((char*)d_ws + 16);
    float* out = (float*)d_out;

    // init: cover P=100k via grid-stride (P only known on device)
    bg_init<<<512, 256, 0, stream>>>(acc, max_bits, num_pids_p);

    // main pass: 2048 blocks x 256 threads, float4/int4 grid-stride
    bg_main<<<2048, 256, 0, stream>>>(beta, pid, acc, max_bits, n);

    // per-pid reduction
    bg_reduce<<<512, 256, 0, stream>>>(max_bits, acc, num_pids_p);

    bg_finalize<<<1, 1, 0, stream>>>(acc, out);
}

// Round 2
// 518.974 us; speedup vs baseline: 1.0332x; 1.0332x over previous
//
#include <hip/hip_runtime.h>

// ws layout:
//   float acc[4]                      @ 0
//     [0] noise_sum  [1] nb  [2] attr_sum  [3] n_valid
//   unsigned int max_bits[ncopies][stride] @ 16
//     max_bits[c][p] = __float_as_uint(max beta for p) + 1; 0 == "absent".
//     Monotone under unsigned compare since beta in [0,1); +1 can't overflow.
//
// ncopies==8: one table copy per XCD, updated with WORKGROUP-scope atomics.
//   Workgroup-scope global atomics execute in the local (per-XCD) L2 with no
//   cross-XCD write-through -- R0 showed device-scope atomics cost 249 MB of
//   memory-side write traffic (31 B/atomic) and 323 us. Each copy is touched
//   only by waves on its own XCD (HW_REG_XCC_ID), so L2-local atomicity is
//   sufficient; end-of-kernel flush makes results visible to bg_reduce.
// ncopies==1: fallback, device-scope atomicMax on a single table.

#define ACC_NOISE  0
#define ACC_NB     1
#define ACC_ATTR   2
#define ACC_NVALID 3

__device__ __forceinline__ int xcc_id() {
    int x;
    asm("s_getreg_b32 %0, hwreg(HW_REG_XCC_ID)" : "=s"(x));
    return x & 7;
}

__global__ void bg_init(float* __restrict__ acc,
                        unsigned int* __restrict__ max_bits,
                        const int* __restrict__ num_pids_p,
                        int ncopies, int stride) {
    const int P = *num_pids_p;
    const int gstride = gridDim.x * blockDim.x;
    const int tid = blockIdx.x * blockDim.x + threadIdx.x;
    if (tid < 4) acc[tid] = 0.0f;
    for (int i = tid; i < P; i += gstride) {
        for (int c = 0; c < ncopies; ++c) {
            max_bits[(size_t)c * stride + i] = 0u;
        }
    }
}

template <bool PER_XCD>
__device__ __forceinline__ void bg_process(int p, float b,
                                           float& noise_local, int& nb_local,
                                           unsigned int* __restrict__ tbl) {
    if (p == 0) {
        noise_local += b;
        nb_local += 1;
    } else {
        unsigned int bits = __float_as_uint(b) + 1u;
        if (PER_XCD) {
            __hip_atomic_fetch_max(&tbl[p], bits, __ATOMIC_RELAXED,
                                   __HIP_MEMORY_SCOPE_WORKGROUP);
        } else {
            atomicMax(&tbl[p], bits);
        }
    }
}

template <bool PER_XCD>
__global__ void bg_main(const float* __restrict__ beta,
                        const int* __restrict__ pid,
                        float* __restrict__ acc,
                        unsigned int* __restrict__ max_bits,
                        int n, int stride) {
    const int gstride = gridDim.x * blockDim.x;
    const int tid = blockIdx.x * blockDim.x + threadIdx.x;
    const int n4 = n >> 2;

    unsigned int* __restrict__ tbl =
        PER_XCD ? (max_bits + (size_t)xcc_id() * stride) : max_bits;

    float noise_local = 0.0f;
    int nb_local = 0;

    const float4* __restrict__ b4 = (const float4*)beta;
    const int4* __restrict__ p4 = (const int4*)pid;
    for (int i = tid; i < n4; i += gstride) {
        float4 b = b4[i];
        int4 p = p4[i];
        bg_process<PER_XCD>(p.x, b.x, noise_local, nb_local, tbl);
        bg_process<PER_XCD>(p.y, b.y, noise_local, nb_local, tbl);
        bg_process<PER_XCD>(p.z, b.z, noise_local, nb_local, tbl);
        bg_process<PER_XCD>(p.w, b.w, noise_local, nb_local, tbl);
    }
    for (int i = (n4 << 2) + tid; i < n; i += gstride) {
        bg_process<PER_XCD>(pid[i], beta[i], noise_local, nb_local, tbl);
    }

    #pragma unroll
    for (int off = 32; off > 0; off >>= 1) {
        noise_local += __shfl_down(noise_local, off);
        nb_local    += __shfl_down(nb_local, off);
    }
    if ((threadIdx.x & 63) == 0 && nb_local != 0) {
        atomicAdd(&acc[ACC_NOISE], noise_local);
        atomicAdd(&acc[ACC_NB], (float)nb_local);
    }
}

__global__ void bg_reduce(const unsigned int* __restrict__ max_bits,
                          float* __restrict__ acc,
                          const int* __restrict__ num_pids_p,
                          int ncopies, int stride) {
    const int P = *num_pids_p;
    const int gstride = gridDim.x * blockDim.x;
    float s = 0.0f;
    int c = 0;
    for (int i = blockIdx.x * blockDim.x + threadIdx.x; i < P; i += gstride) {
        if (i == 0) continue;  // pid 0 is noise, excluded from attractive term
        unsigned int v = 0u;
        for (int k = 0; k < ncopies; ++k) {
            unsigned int u = max_bits[(size_t)k * stride + i];
            v = (u > v) ? u : v;
        }
        if (v != 0u) {
            s += 1.0f - __uint_as_float(v - 1u);
            c += 1;
        }
    }
    #pragma unroll
    for (int off = 32; off > 0; off >>= 1) {
        s += __shfl_down(s, off);
        c += __shfl_down(c, off);
    }
    if ((threadIdx.x & 63) == 0 && (c != 0 || s != 0.0f)) {
        atomicAdd(&acc[ACC_ATTR], s);
        atomicAdd(&acc[ACC_NVALID], (float)c);
    }
}

__global__ void bg_finalize(const float* __restrict__ acc,
                            float* __restrict__ out) {
    float nb = acc[ACC_NB];
    float n_valid = fmaxf(acc[ACC_NVALID], 1.0f);
    float attractive = acc[ACC_ATTR] / n_valid;
    float noise = 0.1f * acc[ACC_NOISE] / fmaxf(nb, 1.0f);
    out[0] = (nb == 0.0f) ? 0.0f : (attractive + noise);
}

extern "C" void kernel_launch(void* const* d_in, const int* in_sizes, int n_in,
                              void* d_out, int out_size, void* d_ws, size_t ws_size,
                              hipStream_t stream) {
    // inputs: 0=w, 1=beta, 2=x, 3=y, 4=particle_id, 5=num_pids (device scalar)
    const float* beta = (const float*)d_in[1];
    const int* pid = (const int*)d_in[4];
    const int* num_pids_p = (const int*)d_in[5];
    const int n = in_sizes[1];

    float* acc = (float*)d_ws;
    unsigned int* max_bits = (unsigned int*)((char*)d_ws + 16);
    float* out = (float*)d_out;

    // P is a device scalar (can't read on host under graph capture); reserve
    // a generous per-copy stride and fall back to one device-scope table if
    // the workspace can't hold 8 copies.
    const size_t STRIDE = 131072;  // > P = 100k
    const bool per_xcd = ws_size >= 16 + 8 * STRIDE * sizeof(unsigned int);
    const int ncopies = per_xcd ? 8 : 1;
    const int stride = per_xcd ? (int)STRIDE
                               : (int)((ws_size - 16) / sizeof(unsigned int));

    bg_init<<<512, 256, 0, stream>>>(acc, max_bits, num_pids_p, ncopies, stride);

    if (per_xcd) {
        bg_main<true><<<2048, 256, 0, stream>>>(beta, pid, acc, max_bits, n, stride);
    } else {
        bg_main<false><<<2048, 256, 0, stream>>>(beta, pid, acc, max_bits, n, stride);
    }

    bg_reduce<<<512, 256, 0, stream>>>(max_bits, acc, num_pids_p, ncopies, stride);

    bg_finalize<<<1, 1, 0, stream>>>(acc, out);
}

// Round 3
// 439.255 us; speedup vs baseline: 1.2207x; 1.1815x over previous
//
#include <hip/hip_runtime.h>

// ws layout:
//   float acc[4] @ 0
//     [0] noise_sum  [1] nb  [2] attr_sum  [3] n_valid
//   unsigned int max_bits[P] @ 16
//     max_bits[p] = __float_as_uint(max beta for p) + 1; 0 == "absent".
//     Monotone under unsigned compare since beta in [0,1); +1 can't overflow.
//
// R0/R1 evidence: device-scope atomicMax costs ~31 B of memory-side write
// traffic each (WRITE_SIZE 249 MB for 8M atomics, 307-323 us) and scope
// hints don't change the lowering. Fix: stale-read filter. The table is
// monotone non-decreasing, so a plain (cacheable, possibly stale) load can
// only UNDER-report the current max -> skipping the atomic when
// bits <= stale_cur is always safe, and a stale read never suppresses a
// genuinely record-setting update (stale <= truth). Expected survivors:
// ~ln(hits_per_pid) per pid plus staleness slack, i.e. >~10x fewer atomics.
// The 400 KB table stays L2-resident, so the filter loads are L2 hits.

#define ACC_NOISE  0
#define ACC_NB     1
#define ACC_ATTR   2
#define ACC_NVALID 3

__global__ void bg_init(float* __restrict__ acc,
                        unsigned int* __restrict__ max_bits,
                        const int* __restrict__ num_pids_p) {
    const int P = *num_pids_p;
    const int gstride = gridDim.x * blockDim.x;
    const int tid = blockIdx.x * blockDim.x + threadIdx.x;
    if (tid < 4) acc[tid] = 0.0f;
    for (int i = tid; i < P; i += gstride) max_bits[i] = 0u;
}

__device__ __forceinline__ void bg_process(int p, float b,
                                           float& noise_local, int& nb_local,
                                           unsigned int* __restrict__ tbl) {
    if (p == 0) {
        noise_local += b;
        nb_local += 1;
    } else {
        unsigned int bits = __float_as_uint(b) + 1u;
        // Stale-read filter: cacheable load; stale <= truth (monotone table),
        // so this never skips a required atomic, only redundant ones.
        unsigned int cur = tbl[p];
        if (bits > cur) {
            atomicMax(&tbl[p], bits);
        }
    }
}

__global__ void bg_main(const float* __restrict__ beta,
                        const int* __restrict__ pid,
                        float* __restrict__ acc,
                        unsigned int* __restrict__ max_bits,
                        int n) {
    const int gstride = gridDim.x * blockDim.x;
    const int tid = blockIdx.x * blockDim.x + threadIdx.x;
    const int n4 = n >> 2;

    float noise_local = 0.0f;
    int nb_local = 0;

    const float4* __restrict__ b4 = (const float4*)beta;
    const int4* __restrict__ p4 = (const int4*)pid;
    for (int i = tid; i < n4; i += gstride) {
        float4 b = b4[i];
        int4 p = p4[i];
        bg_process(p.x, b.x, noise_local, nb_local, max_bits);
        bg_process(p.y, b.y, noise_local, nb_local, max_bits);
        bg_process(p.z, b.z, noise_local, nb_local, max_bits);
        bg_process(p.w, b.w, noise_local, nb_local, max_bits);
    }
    for (int i = (n4 << 2) + tid; i < n; i += gstride) {
        bg_process(pid[i], beta[i], noise_local, nb_local, max_bits);
    }

    #pragma unroll
    for (int off = 32; off > 0; off >>= 1) {
        noise_local += __shfl_down(noise_local, off);
        nb_local    += __shfl_down(nb_local, off);
    }
    if ((threadIdx.x & 63) == 0 && nb_local != 0) {
        atomicAdd(&acc[ACC_NOISE], noise_local);
        atomicAdd(&acc[ACC_NB], (float)nb_local);
    }
}

__global__ void bg_reduce(const unsigned int* __restrict__ max_bits,
                          float* __restrict__ acc,
                          const int* __restrict__ num_pids_p) {
    const int P = *num_pids_p;
    const int gstride = gridDim.x * blockDim.x;
    float s = 0.0f;
    int c = 0;
    for (int i = blockIdx.x * blockDim.x + threadIdx.x; i < P; i += gstride) {
        if (i == 0) continue;  // pid 0 is noise, excluded from attractive term
        unsigned int v = max_bits[i];
        if (v != 0u) {
            s += 1.0f - __uint_as_float(v - 1u);
            c += 1;
        }
    }
    #pragma unroll
    for (int off = 32; off > 0; off >>= 1) {
        s += __shfl_down(s, off);
        c += __shfl_down(c, off);
    }
    if ((threadIdx.x & 63) == 0 && (c != 0 || s != 0.0f)) {
        atomicAdd(&acc[ACC_ATTR], s);
        atomicAdd(&acc[ACC_NVALID], (float)c);
    }
}

__global__ void bg_finalize(const float* __restrict__ acc,
                            float* __restrict__ out) {
    float nb = acc[ACC_NB];
    float n_valid = fmaxf(acc[ACC_NVALID], 1.0f);
    float attractive = acc[ACC_ATTR] / n_valid;
    float noise = 0.1f * acc[ACC_NOISE] / fmaxf(nb, 1.0f);
    out[0] = (nb == 0.0f) ? 0.0f : (attractive + noise);
}

extern "C" void kernel_launch(void* const* d_in, const int* in_sizes, int n_in,
                              void* d_out, int out_size, void* d_ws, size_t ws_size,
                              hipStream_t stream) {
    // inputs: 0=w, 1=beta, 2=x, 3=y, 4=particle_id, 5=num_pids (device scalar)
    const float* beta = (const float*)d_in[1];
    const int* pid = (const int*)d_in[4];
    const int* num_pids_p = (const int*)d_in[5];
    const int n = in_sizes[1];

    float* acc = (float*)d_ws;
    unsigned int* max_bits = (unsigned int*)((char*)d_ws + 16);
    float* out = (float*)d_out;

    bg_init<<<512, 256, 0, stream>>>(acc, max_bits, num_pids_p);
    bg_main<<<2048, 256, 0, stream>>>(beta, pid, acc, max_bits, n);
    bg_reduce<<<512, 256, 0, stream>>>(max_bits, acc, num_pids_p);
    bg_finalize<<<1, 1, 0, stream>>>(acc, out);
}

// Round 4
// 278.671 us; speedup vs baseline: 1.9241x; 1.5763x over previous
//
#include <hip/hip_runtime.h>

// ws layout (slab path, needs 16 + 32 MB):
//   float acc[4] @ 0          [0]=noise_sum [1]=nb [2]=attr_sum [3]=n_valid
//   unsigned slabs[NRANGE*BPR][RANGE] @ 16
//
// R0-R2 evidence: device-scope atomics AND their line invalidations both
// funnel through the memory-side coherence point at ~500-800 GB/s effective
// (R0: 249 MB write, 323 us; R2: filter cut writes 10x but added 91 MB of
// invalidation refetch, 228 us). Fix: no global-table traffic in the hot
// loop at all. Pid-space is split into NRANGE ranges of RANGE pids; each
// range-group of BPR blocks streams the whole input (L3-resident after the
// first pass) and maxes into a private 64 KB LDS table (per-CU atomics,
// ~free), then dumps it to a private slab (coalesced stores). bg_reduce
// maxes across the BPR slabs per range. value = float_bits(beta)+1, 0 =
// "absent" (monotone for beta in [0,1), +1 can't overflow).
// Fallback (ws too small): R2's stale-read-filtered global atomicMax.

#define ACC_NOISE  0
#define ACC_NB     1
#define ACC_ATTR   2
#define ACC_NVALID 3

#define RANGE_BITS 14
#define RANGE      (1 << RANGE_BITS)   // 16384 pids/range, 64 KB LDS
#define NRANGE     8                   // covers 131072 >= P = 100000
#define BPR        64                  // blocks per range
#define TPB        256

// ---------------- slab path ----------------

__global__ void bg_init_acc(float* __restrict__ acc) {
    if (threadIdx.x < 4) acc[threadIdx.x] = 0.0f;
}

__global__ __launch_bounds__(TPB) void bg_main_lds(
        const float* __restrict__ beta, const int* __restrict__ pid,
        float* __restrict__ acc, unsigned int* __restrict__ slabs, int n) {
    __shared__ unsigned int tbl[RANGE];
    const int r = blockIdx.x / BPR;
    const int b = blockIdx.x % BPR;
    const int lo = r << RANGE_BITS;

    for (int i = threadIdx.x; i < RANGE; i += TPB) tbl[i] = 0u;
    __syncthreads();

    float noise_local = 0.0f;
    int nb_local = 0;

    const int n4 = n >> 2;
    const float4* __restrict__ b4 = (const float4*)beta;
    const int4* __restrict__ p4 = (const int4*)pid;
    const int gtid = b * TPB + (int)threadIdx.x;
    const int gstride = BPR * TPB;

    // process one (pid, beta) hit against this block's range
    auto proc = [&](int p, float v) {
        int d = p - lo;
        if ((unsigned)d < (unsigned)RANGE) {
            if (p == 0) {            // only reachable in range 0
                noise_local += v;
                nb_local += 1;
            } else {
                atomicMax(&tbl[d], __float_as_uint(v) + 1u);
            }
        }
    };

    int i = gtid;
    for (; i + gstride < n4; i += 2 * gstride) {   // 2x unroll for MLP
        float4 bb0 = b4[i];           int4 pp0 = p4[i];
        float4 bb1 = b4[i + gstride]; int4 pp1 = p4[i + gstride];
        proc(pp0.x, bb0.x); proc(pp0.y, bb0.y);
        proc(pp0.z, bb0.z); proc(pp0.w, bb0.w);
        proc(pp1.x, bb1.x); proc(pp1.y, bb1.y);
        proc(pp1.z, bb1.z); proc(pp1.w, bb1.w);
    }
    if (i < n4) {
        float4 bb = b4[i]; int4 pp = p4[i];
        proc(pp.x, bb.x); proc(pp.y, bb.y);
        proc(pp.z, bb.z); proc(pp.w, bb.w);
    }
    if (b == 0) {  // tail (n % 4): block 0 of each range scans it
        for (int t = (n4 << 2) + (int)threadIdx.x; t < n; t += TPB)
            proc(pid[t], beta[t]);
    }

    // noise contributions exist only in range-0 blocks
    #pragma unroll
    for (int off = 32; off > 0; off >>= 1) {
        noise_local += __shfl_down(noise_local, off);
        nb_local    += __shfl_down(nb_local, off);
    }
    if ((threadIdx.x & 63) == 0 && nb_local != 0) {
        atomicAdd(&acc[ACC_NOISE], noise_local);
        atomicAdd(&acc[ACC_NB], (float)nb_local);
    }

    __syncthreads();
    // dump private table to slab (coalesced uint4)
    uint4* __restrict__ o4 = (uint4*)(slabs + (size_t)blockIdx.x * RANGE);
    const uint4* __restrict__ t4 = (const uint4*)tbl;
    for (int k = threadIdx.x; k < RANGE / 4; k += TPB) o4[k] = t4[k];
}

__global__ __launch_bounds__(TPB) void bg_reduce_slab(
        const unsigned int* __restrict__ slabs, float* __restrict__ acc,
        const int* __restrict__ num_pids_p) {
    const int P = *num_pids_p;
    const int t = blockIdx.x * TPB + (int)threadIdx.x;  // grid = NRANGE*RANGE threads
    const int e = t & (RANGE - 1);
    const int r = t >> RANGE_BITS;

    unsigned int v = 0u;
    const unsigned int* __restrict__ base =
        slabs + (size_t)(r * BPR) * RANGE + e;
    #pragma unroll 4
    for (int b = 0; b < BPR; ++b) {
        unsigned int u = base[(size_t)b * RANGE];
        v = (u > v) ? u : v;
    }

    const int p = (r << RANGE_BITS) | e;
    float s = 0.0f;
    int c = 0;
    if (p > 0 && p < P && v != 0u) {
        s = 1.0f - __uint_as_float(v - 1u);
        c = 1;
    }
    #pragma unroll
    for (int off = 32; off > 0; off >>= 1) {
        s += __shfl_down(s, off);
        c += __shfl_down(c, off);
    }
    if ((threadIdx.x & 63) == 0 && (c != 0 || s != 0.0f)) {
        atomicAdd(&acc[ACC_ATTR], s);
        atomicAdd(&acc[ACC_NVALID], (float)c);
    }
}

// ---------------- fallback path (R2) ----------------

__global__ void bg_init(float* __restrict__ acc,
                        unsigned int* __restrict__ max_bits,
                        const int* __restrict__ num_pids_p) {
    const int P = *num_pids_p;
    const int gstride = gridDim.x * blockDim.x;
    const int tid = blockIdx.x * blockDim.x + threadIdx.x;
    if (tid < 4) acc[tid] = 0.0f;
    for (int i = tid; i < P; i += gstride) max_bits[i] = 0u;
}

__device__ __forceinline__ void bg_process(int p, float b,
                                           float& noise_local, int& nb_local,
                                           unsigned int* __restrict__ tbl) {
    if (p == 0) {
        noise_local += b;
        nb_local += 1;
    } else {
        unsigned int bits = __float_as_uint(b) + 1u;
        unsigned int cur = tbl[p];          // stale-read filter (monotone)
        if (bits > cur) atomicMax(&tbl[p], bits);
    }
}

__global__ void bg_main(const float* __restrict__ beta,
                        const int* __restrict__ pid,
                        float* __restrict__ acc,
                        unsigned int* __restrict__ max_bits, int n) {
    const int gstride = gridDim.x * blockDim.x;
    const int tid = blockIdx.x * blockDim.x + threadIdx.x;
    const int n4 = n >> 2;
    float noise_local = 0.0f;
    int nb_local = 0;
    const float4* __restrict__ b4 = (const float4*)beta;
    const int4* __restrict__ p4 = (const int4*)pid;
    for (int i = tid; i < n4; i += gstride) {
        float4 b = b4[i]; int4 p = p4[i];
        bg_process(p.x, b.x, noise_local, nb_local, max_bits);
        bg_process(p.y, b.y, noise_local, nb_local, max_bits);
        bg_process(p.z, b.z, noise_local, nb_local, max_bits);
        bg_process(p.w, b.w, noise_local, nb_local, max_bits);
    }
    for (int i = (n4 << 2) + tid; i < n; i += gstride)
        bg_process(pid[i], beta[i], noise_local, nb_local, max_bits);
    #pragma unroll
    for (int off = 32; off > 0; off >>= 1) {
        noise_local += __shfl_down(noise_local, off);
        nb_local    += __shfl_down(nb_local, off);
    }
    if ((threadIdx.x & 63) == 0 && nb_local != 0) {
        atomicAdd(&acc[ACC_NOISE], noise_local);
        atomicAdd(&acc[ACC_NB], (float)nb_local);
    }
}

__global__ void bg_reduce(const unsigned int* __restrict__ max_bits,
                          float* __restrict__ acc,
                          const int* __restrict__ num_pids_p) {
    const int P = *num_pids_p;
    const int gstride = gridDim.x * blockDim.x;
    float s = 0.0f;
    int c = 0;
    for (int i = blockIdx.x * blockDim.x + threadIdx.x; i < P; i += gstride) {
        if (i == 0) continue;
        unsigned int v = max_bits[i];
        if (v != 0u) { s += 1.0f - __uint_as_float(v - 1u); c += 1; }
    }
    #pragma unroll
    for (int off = 32; off > 0; off >>= 1) {
        s += __shfl_down(s, off);
        c += __shfl_down(c, off);
    }
    if ((threadIdx.x & 63) == 0 && (c != 0 || s != 0.0f)) {
        atomicAdd(&acc[ACC_ATTR], s);
        atomicAdd(&acc[ACC_NVALID], (float)c);
    }
}

// ---------------- shared finalize ----------------

__global__ void bg_finalize(const float* __restrict__ acc,
                            float* __restrict__ out) {
    float nb = acc[ACC_NB];
    float n_valid = fmaxf(acc[ACC_NVALID], 1.0f);
    float attractive = acc[ACC_ATTR] / n_valid;
    float noise = 0.1f * acc[ACC_NOISE] / fmaxf(nb, 1.0f);
    out[0] = (nb == 0.0f) ? 0.0f : (attractive + noise);
}

extern "C" void kernel_launch(void* const* d_in, const int* in_sizes, int n_in,
                              void* d_out, int out_size, void* d_ws, size_t ws_size,
                              hipStream_t stream) {
    // inputs: 0=w, 1=beta, 2=x, 3=y, 4=particle_id, 5=num_pids (device scalar)
    const float* beta = (const float*)d_in[1];
    const int* pid = (const int*)d_in[4];
    const int* num_pids_p = (const int*)d_in[5];
    const int n = in_sizes[1];

    float* acc = (float*)d_ws;
    float* out = (float*)d_out;

    const size_t slab_bytes = (size_t)NRANGE * BPR * RANGE * sizeof(unsigned int);
    if (ws_size >= 16 + slab_bytes) {
        unsigned int* slabs = (unsigned int*)((char*)d_ws + 16);
        bg_init_acc<<<1, 64, 0, stream>>>(acc);
        bg_main_lds<<<NRANGE * BPR, TPB, 0, stream>>>(beta, pid, acc, slabs, n);
        bg_reduce_slab<<<(NRANGE * RANGE) / TPB, TPB, 0, stream>>>(slabs, acc, num_pids_p);
        bg_finalize<<<1, 1, 0, stream>>>(acc, out);
    } else {
        unsigned int* max_bits = (unsigned int*)((char*)d_ws + 16);
        bg_init<<<512, 256, 0, stream>>>(acc, max_bits, num_pids_p);
        bg_main<<<2048, 256, 0, stream>>>(beta, pid, acc, max_bits, n);
        bg_reduce<<<512, 256, 0, stream>>>(max_bits, acc, num_pids_p);
        bg_finalize<<<1, 1, 0, stream>>>(acc, out);
    }
}

// Round 5
// 266.319 us; speedup vs baseline: 2.0133x; 1.0464x over previous
//
#include <hip/hip_runtime.h>

// ws layout (slab path, needs 16 + 32 MB):
//   float acc[4] @ 0          [0]=noise_sum [1]=nb [2]=attr_sum [3]=n_valid
//   unsigned slabs[NRANGE*BPR][RANGE] @ 16
//
// Evidence trail:
//   R0: 8M device atomicMax -> 249 MB memory-side write traffic, 323 us.
//   R1: scope hints don't change atomic lowering (identical WRITE_SIZE).
//   R2: stale-read filter cut atomics 10x but line invalidations added
//       91 MB of coherence-path refetch; 228 us.
//   R3: pid-range partitioning w/ private 64 KB LDS tables + slab dump:
//       70 us, WRITE 33 MB, FETCH 31 MB (8x input re-read served by L3).
//       Occupancy 18.9% (2 blocks/CU from LDS, TPB=256 -> 8 waves/CU),
//       VALUBusy 16%, conflicts negligible -> latency-bound on L3 loads.
//   R4: TPB 256->512 (16 waves/CU, 2x latency hiding) + LDS stale-read
//       filter before the LDS atomic.
// value = float_bits(beta)+1, 0 = "absent" (monotone for beta in [0,1)).
// Fallback (ws too small): R2's stale-read-filtered global atomicMax.

#define ACC_NOISE  0
#define ACC_NB     1
#define ACC_ATTR   2
#define ACC_NVALID 3

#define RANGE_BITS 14
#define RANGE      (1 << RANGE_BITS)   // 16384 pids/range, 64 KB LDS
#define NRANGE     8                   // covers 131072 >= P = 100000
#define BPR        64                  // blocks per range
#define TPB        512                 // 2 blocks/CU * 8 waves = 16 waves/CU

// ---------------- slab path ----------------

__global__ void bg_init_acc(float* __restrict__ acc) {
    if (threadIdx.x < 4) acc[threadIdx.x] = 0.0f;
}

__global__ __launch_bounds__(TPB) void bg_main_lds(
        const float* __restrict__ beta, const int* __restrict__ pid,
        float* __restrict__ acc, unsigned int* __restrict__ slabs, int n) {
    __shared__ unsigned int tbl[RANGE];
    const int r = blockIdx.x / BPR;
    const int b = blockIdx.x % BPR;
    const int lo = r << RANGE_BITS;

    for (int i = threadIdx.x; i < RANGE; i += TPB) tbl[i] = 0u;
    __syncthreads();

    float noise_local = 0.0f;
    int nb_local = 0;

    const int n4 = n >> 2;
    const float4* __restrict__ b4 = (const float4*)beta;
    const int4* __restrict__ p4 = (const int4*)pid;
    const int gtid = b * TPB + (int)threadIdx.x;
    const int gstride = BPR * TPB;

    // process one (pid, beta) hit against this block's range
    auto proc = [&](int p, float v) {
        int d = p - lo;
        if ((unsigned)d < (unsigned)RANGE) {
            if (p == 0) {            // only reachable in range 0
                noise_local += v;
                nb_local += 1;
            } else {
                unsigned int bits = __float_as_uint(v) + 1u;
                // stale-read filter: tbl is monotone non-decreasing, so a
                // plain ds_read can only under-report -> skipping when
                // bits <= cur is safe and avoids ~94% of DS atomics.
                if (bits > tbl[d]) atomicMax(&tbl[d], bits);
            }
        }
    };

    int i = gtid;
    for (; i + gstride < n4; i += 2 * gstride) {   // 2x unroll for MLP
        float4 bb0 = b4[i];           int4 pp0 = p4[i];
        float4 bb1 = b4[i + gstride]; int4 pp1 = p4[i + gstride];
        proc(pp0.x, bb0.x); proc(pp0.y, bb0.y);
        proc(pp0.z, bb0.z); proc(pp0.w, bb0.w);
        proc(pp1.x, bb1.x); proc(pp1.y, bb1.y);
        proc(pp1.z, bb1.z); proc(pp1.w, bb1.w);
    }
    if (i < n4) {
        float4 bb = b4[i]; int4 pp = p4[i];
        proc(pp.x, bb.x); proc(pp.y, bb.y);
        proc(pp.z, bb.z); proc(pp.w, bb.w);
    }
    if (b == 0) {  // tail (n % 4): block 0 of each range scans it
        for (int t = (n4 << 2) + (int)threadIdx.x; t < n; t += TPB)
            proc(pid[t], beta[t]);
    }

    // noise contributions exist only in range-0 blocks
    #pragma unroll
    for (int off = 32; off > 0; off >>= 1) {
        noise_local += __shfl_down(noise_local, off);
        nb_local    += __shfl_down(nb_local, off);
    }
    if ((threadIdx.x & 63) == 0 && nb_local != 0) {
        atomicAdd(&acc[ACC_NOISE], noise_local);
        atomicAdd(&acc[ACC_NB], (float)nb_local);
    }

    __syncthreads();
    // dump private table to slab (coalesced uint4)
    uint4* __restrict__ o4 = (uint4*)(slabs + (size_t)blockIdx.x * RANGE);
    const uint4* __restrict__ t4 = (const uint4*)tbl;
    for (int k = threadIdx.x; k < RANGE / 4; k += TPB) o4[k] = t4[k];
}

__global__ __launch_bounds__(256) void bg_reduce_slab(
        const unsigned int* __restrict__ slabs, float* __restrict__ acc,
        const int* __restrict__ num_pids_p) {
    const int P = *num_pids_p;
    const int t = blockIdx.x * 256 + (int)threadIdx.x;  // grid = NRANGE*RANGE threads
    const int e = t & (RANGE - 1);
    const int r = t >> RANGE_BITS;

    unsigned int v = 0u;
    const unsigned int* __restrict__ base =
        slabs + (size_t)(r * BPR) * RANGE + e;
    #pragma unroll 4
    for (int b = 0; b < BPR; ++b) {
        unsigned int u = base[(size_t)b * RANGE];
        v = (u > v) ? u : v;
    }

    const int p = (r << RANGE_BITS) | e;
    float s = 0.0f;
    int c = 0;
    if (p > 0 && p < P && v != 0u) {
        s = 1.0f - __uint_as_float(v - 1u);
        c = 1;
    }
    #pragma unroll
    for (int off = 32; off > 0; off >>= 1) {
        s += __shfl_down(s, off);
        c += __shfl_down(c, off);
    }
    if ((threadIdx.x & 63) == 0 && (c != 0 || s != 0.0f)) {
        atomicAdd(&acc[ACC_ATTR], s);
        atomicAdd(&acc[ACC_NVALID], (float)c);
    }
}

// ---------------- fallback path (R2) ----------------

__global__ void bg_init(float* __restrict__ acc,
                        unsigned int* __restrict__ max_bits,
                        const int* __restrict__ num_pids_p) {
    const int P = *num_pids_p;
    const int gstride = gridDim.x * blockDim.x;
    const int tid = blockIdx.x * blockDim.x + threadIdx.x;
    if (tid < 4) acc[tid] = 0.0f;
    for (int i = tid; i < P; i += gstride) max_bits[i] = 0u;
}

__device__ __forceinline__ void bg_process(int p, float b,
                                           float& noise_local, int& nb_local,
                                           unsigned int* __restrict__ tbl) {
    if (p == 0) {
        noise_local += b;
        nb_local += 1;
    } else {
        unsigned int bits = __float_as_uint(b) + 1u;
        unsigned int cur = tbl[p];          // stale-read filter (monotone)
        if (bits > cur) atomicMax(&tbl[p], bits);
    }
}

__global__ void bg_main(const float* __restrict__ beta,
                        const int* __restrict__ pid,
                        float* __restrict__ acc,
                        unsigned int* __restrict__ max_bits, int n) {
    const int gstride = gridDim.x * blockDim.x;
    const int tid = blockIdx.x * blockDim.x + threadIdx.x;
    const int n4 = n >> 2;
    float noise_local = 0.0f;
    int nb_local = 0;
    const float4* __restrict__ b4 = (const float4*)beta;
    const int4* __restrict__ p4 = (const int4*)pid;
    for (int i = tid; i < n4; i += gstride) {
        float4 b = b4[i]; int4 p = p4[i];
        bg_process(p.x, b.x, noise_local, nb_local, max_bits);
        bg_process(p.y, b.y, noise_local, nb_local, max_bits);
        bg_process(p.z, b.z, noise_local, nb_local, max_bits);
        bg_process(p.w, b.w, noise_local, nb_local, max_bits);
    }
    for (int i = (n4 << 2) + tid; i < n; i += gstride)
        bg_process(pid[i], beta[i], noise_local, nb_local, max_bits);
    #pragma unroll
    for (int off = 32; off > 0; off >>= 1) {
        noise_local += __shfl_down(noise_local, off);
        nb_local    += __shfl_down(nb_local, off);
    }
    if ((threadIdx.x & 63) == 0 && nb_local != 0) {
        atomicAdd(&acc[ACC_NOISE], noise_local);
        atomicAdd(&acc[ACC_NB], (float)nb_local);
    }
}

__global__ void bg_reduce(const unsigned int* __restrict__ max_bits,
                          float* __restrict__ acc,
                          const int* __restrict__ num_pids_p) {
    const int P = *num_pids_p;
    const int gstride = gridDim.x * blockDim.x;
    float s = 0.0f;
    int c = 0;
    for (int i = blockIdx.x * blockDim.x + threadIdx.x; i < P; i += gstride) {
        if (i == 0) continue;
        unsigned int v = max_bits[i];
        if (v != 0u) { s += 1.0f - __uint_as_float(v - 1u); c += 1; }
    }
    #pragma unroll
    for (int off = 32; off > 0; off >>= 1) {
        s += __shfl_down(s, off);
        c += __shfl_down(c, off);
    }
    if ((threadIdx.x & 63) == 0 && (c != 0 || s != 0.0f)) {
        atomicAdd(&acc[ACC_ATTR], s);
        atomicAdd(&acc[ACC_NVALID], (float)c);
    }
}

// ---------------- shared finalize ----------------

__global__ void bg_finalize(const float* __restrict__ acc,
                            float* __restrict__ out) {
    float nb = acc[ACC_NB];
    float n_valid = fmaxf(acc[ACC_NVALID], 1.0f);
    float attractive = acc[ACC_ATTR] / n_valid;
    float noise = 0.1f * acc[ACC_NOISE] / fmaxf(nb, 1.0f);
    out[0] = (nb == 0.0f) ? 0.0f : (attractive + noise);
}

extern "C" void kernel_launch(void* const* d_in, const int* in_sizes, int n_in,
                              void* d_out, int out_size, void* d_ws, size_t ws_size,
                              hipStream_t stream) {
    // inputs: 0=w, 1=beta, 2=x, 3=y, 4=particle_id, 5=num_pids (device scalar)
    const float* beta = (const float*)d_in[1];
    const int* pid = (const int*)d_in[4];
    const int* num_pids_p = (const int*)d_in[5];
    const int n = in_sizes[1];

    float* acc = (float*)d_ws;
    float* out = (float*)d_out;

    const size_t slab_bytes = (size_t)NRANGE * BPR * RANGE * sizeof(unsigned int);
    if (ws_size >= 16 + slab_bytes) {
        unsigned int* slabs = (unsigned int*)((char*)d_ws + 16);
        bg_init_acc<<<1, 64, 0, stream>>>(acc);
        bg_main_lds<<<NRANGE * BPR, TPB, 0, stream>>>(beta, pid, acc, slabs, n);
        bg_reduce_slab<<<(NRANGE * RANGE) / 256, 256, 0, stream>>>(slabs, acc, num_pids_p);
        bg_finalize<<<1, 1, 0, stream>>>(acc, out);
    } else {
        unsigned int* max_bits = (unsigned int*)((char*)d_ws + 16);
        bg_init<<<512, 256, 0, stream>>>(acc, max_bits, num_pids_p);
        bg_main<<<2048, 256, 0, stream>>>(beta, pid, acc, max_bits, n);
        bg_reduce<<<512, 256, 0, stream>>>(max_bits, acc, num_pids_p);
        bg_finalize<<<1, 1, 0, stream>>>(acc, out);
    }
}

// Round 6
// 247.925 us; speedup vs baseline: 2.1627x; 1.0742x over previous
//
#include <hip/hip_runtime.h>

// ws layout (slab paths, need 16 + 32 MB):
//   float acc[4] @ 0          [0]=noise_sum [1]=nb [2]=attr_sum [3]=n_valid
//   unsigned slabs[...] @ 16  (256 slabs x RANGE entries; 32 MB both paths)
//
// Evidence trail:
//   R0: 8M device atomicMax -> 249 MB memory-side write traffic, 323 us.
//   R1: scope hints don't change atomic lowering (identical WRITE_SIZE).
//   R2: stale-read filter cut atomics 10x but line invalidations added
//       91 MB coherence refetch; 228 us.
//   R3: pid-range partitioning, private 64 KB LDS tables + slab dump:
//       70 us; 8x64 MB input re-reads fully L3-served (FETCH stays 31 MB).
//   R4: TPB 256->512 gave only 1.23x (70->57 us) -> transitioning to
//       L3-BW-bound: 512 MB / 57 us = 9.0 TB/s ~ Infinity Cache ceiling.
//   R5: halve traffic: 128 KB dynamic-LDS table (CDNA4 LDS = 160 KB/CU),
//       RANGE 16384->32768, NRANGE 8->4 -> 256 MB of L3 reads.
// value = float_bits(beta)+1, 0 = "absent" (monotone for beta in [0,1)).
// Fallbacks: 64 KB static-LDS path (R4), then global-atomic path (R2).

#define ACC_NOISE  0
#define ACC_NB     1
#define ACC_ATTR   2
#define ACC_NVALID 3

// big path (128 KB dynamic LDS)
#define RANGE_BITS_BIG 15
#define RANGE_BIG      (1 << RANGE_BITS_BIG)   // 32768 pids, 128 KB LDS
#define NRANGE_BIG     4                        // covers 131072 >= P
#define TPB_BIG        1024                     // 1 block/CU, 16 waves/CU

// small path (64 KB static LDS)
#define RANGE_BITS 14
#define RANGE      (1 << RANGE_BITS)   // 16384 pids, 64 KB LDS
#define NRANGE     8
#define TPB        512                 // 2 blocks/CU * 8 waves = 16 waves/CU

#define BPR        64                  // blocks per range (both paths)

__global__ void bg_init_acc(float* __restrict__ acc) {
    if (threadIdx.x < 4) acc[threadIdx.x] = 0.0f;
}

// ---------------- big path: 128 KB dynamic LDS ----------------

__global__ __launch_bounds__(TPB_BIG) void bg_main_big(
        const float* __restrict__ beta, const int* __restrict__ pid,
        float* __restrict__ acc, unsigned int* __restrict__ slabs, int n) {
    extern __shared__ unsigned int tbl[];          // RANGE_BIG entries
    const int r = blockIdx.x / BPR;
    const int b = blockIdx.x % BPR;
    const int lo = r << RANGE_BITS_BIG;

    for (int i = threadIdx.x; i < RANGE_BIG; i += TPB_BIG) tbl[i] = 0u;
    __syncthreads();

    float noise_local = 0.0f;
    int nb_local = 0;

    const int n4 = n >> 2;
    const float4* __restrict__ b4 = (const float4*)beta;
    const int4* __restrict__ p4 = (const int4*)pid;
    const int gtid = b * TPB_BIG + (int)threadIdx.x;
    const int gstride = BPR * TPB_BIG;

    auto proc = [&](int p, float v) {
        int d = p - lo;
        if ((unsigned)d < (unsigned)RANGE_BIG) {
            if (p == 0) {                 // only reachable in range 0
                noise_local += v;
                nb_local += 1;
            } else {
                unsigned int bits = __float_as_uint(v) + 1u;
                // stale-read filter: monotone table, skip is always safe
                if (bits > tbl[d]) atomicMax(&tbl[d], bits);
            }
        }
    };

    int i = gtid;
    for (; i + gstride < n4; i += 2 * gstride) {   // 2x unroll for MLP
        float4 bb0 = b4[i];           int4 pp0 = p4[i];
        float4 bb1 = b4[i + gstride]; int4 pp1 = p4[i + gstride];
        proc(pp0.x, bb0.x); proc(pp0.y, bb0.y);
        proc(pp0.z, bb0.z); proc(pp0.w, bb0.w);
        proc(pp1.x, bb1.x); proc(pp1.y, bb1.y);
        proc(pp1.z, bb1.z); proc(pp1.w, bb1.w);
    }
    if (i < n4) {
        float4 bb = b4[i]; int4 pp = p4[i];
        proc(pp.x, bb.x); proc(pp.y, bb.y);
        proc(pp.z, bb.z); proc(pp.w, bb.w);
    }
    if (b == 0) {  // tail (n % 4)
        for (int t = (n4 << 2) + (int)threadIdx.x; t < n; t += TPB_BIG)
            proc(pid[t], beta[t]);
    }

    #pragma unroll
    for (int off = 32; off > 0; off >>= 1) {
        noise_local += __shfl_down(noise_local, off);
        nb_local    += __shfl_down(nb_local, off);
    }
    if ((threadIdx.x & 63) == 0 && nb_local != 0) {
        atomicAdd(&acc[ACC_NOISE], noise_local);
        atomicAdd(&acc[ACC_NB], (float)nb_local);
    }

    __syncthreads();
    uint4* __restrict__ o4 = (uint4*)(slabs + (size_t)blockIdx.x * RANGE_BIG);
    const uint4* __restrict__ t4 = (const uint4*)tbl;
    for (int k = threadIdx.x; k < RANGE_BIG / 4; k += TPB_BIG) o4[k] = t4[k];
}

// ---------------- small path: 64 KB static LDS (R4) ----------------

__global__ __launch_bounds__(TPB) void bg_main_lds(
        const float* __restrict__ beta, const int* __restrict__ pid,
        float* __restrict__ acc, unsigned int* __restrict__ slabs, int n) {
    __shared__ unsigned int tbl[RANGE];
    const int r = blockIdx.x / BPR;
    const int b = blockIdx.x % BPR;
    const int lo = r << RANGE_BITS;

    for (int i = threadIdx.x; i < RANGE; i += TPB) tbl[i] = 0u;
    __syncthreads();

    float noise_local = 0.0f;
    int nb_local = 0;

    const int n4 = n >> 2;
    const float4* __restrict__ b4 = (const float4*)beta;
    const int4* __restrict__ p4 = (const int4*)pid;
    const int gtid = b * TPB + (int)threadIdx.x;
    const int gstride = BPR * TPB;

    auto proc = [&](int p, float v) {
        int d = p - lo;
        if ((unsigned)d < (unsigned)RANGE) {
            if (p == 0) {
                noise_local += v;
                nb_local += 1;
            } else {
                unsigned int bits = __float_as_uint(v) + 1u;
                if (bits > tbl[d]) atomicMax(&tbl[d], bits);
            }
        }
    };

    int i = gtid;
    for (; i + gstride < n4; i += 2 * gstride) {
        float4 bb0 = b4[i];           int4 pp0 = p4[i];
        float4 bb1 = b4[i + gstride]; int4 pp1 = p4[i + gstride];
        proc(pp0.x, bb0.x); proc(pp0.y, bb0.y);
        proc(pp0.z, bb0.z); proc(pp0.w, bb0.w);
        proc(pp1.x, bb1.x); proc(pp1.y, bb1.y);
        proc(pp1.z, bb1.z); proc(pp1.w, bb1.w);
    }
    if (i < n4) {
        float4 bb = b4[i]; int4 pp = p4[i];
        proc(pp.x, bb.x); proc(pp.y, bb.y);
        proc(pp.z, bb.z); proc(pp.w, bb.w);
    }
    if (b == 0) {
        for (int t = (n4 << 2) + (int)threadIdx.x; t < n; t += TPB)
            proc(pid[t], beta[t]);
    }

    #pragma unroll
    for (int off = 32; off > 0; off >>= 1) {
        noise_local += __shfl_down(noise_local, off);
        nb_local    += __shfl_down(nb_local, off);
    }
    if ((threadIdx.x & 63) == 0 && nb_local != 0) {
        atomicAdd(&acc[ACC_NOISE], noise_local);
        atomicAdd(&acc[ACC_NB], (float)nb_local);
    }

    __syncthreads();
    uint4* __restrict__ o4 = (uint4*)(slabs + (size_t)blockIdx.x * RANGE);
    const uint4* __restrict__ t4 = (const uint4*)tbl;
    for (int k = threadIdx.x; k < RANGE / 4; k += TPB) o4[k] = t4[k];
}

// ---------------- shared slab reduce (templated on geometry) ----------------

template <int RBITS>
__global__ __launch_bounds__(256) void bg_reduce_slab_t(
        const unsigned int* __restrict__ slabs, float* __restrict__ acc,
        const int* __restrict__ num_pids_p) {
    const int RSZ = 1 << RBITS;
    const int P = *num_pids_p;
    const int t = blockIdx.x * 256 + (int)threadIdx.x;
    const int e = t & (RSZ - 1);
    const int r = t >> RBITS;

    unsigned int v = 0u;
    const unsigned int* __restrict__ base =
        slabs + (size_t)(r * BPR) * RSZ + e;
    #pragma unroll 4
    for (int b = 0; b < BPR; ++b) {
        unsigned int u = base[(size_t)b * RSZ];
        v = (u > v) ? u : v;
    }

    const int p = (r << RBITS) | e;
    float s = 0.0f;
    int c = 0;
    if (p > 0 && p < P && v != 0u) {
        s = 1.0f - __uint_as_float(v - 1u);
        c = 1;
    }
    #pragma unroll
    for (int off = 32; off > 0; off >>= 1) {
        s += __shfl_down(s, off);
        c += __shfl_down(c, off);
    }
    if ((threadIdx.x & 63) == 0 && (c != 0 || s != 0.0f)) {
        atomicAdd(&acc[ACC_ATTR], s);
        atomicAdd(&acc[ACC_NVALID], (float)c);
    }
}

// ---------------- global-atomic fallback (R2) ----------------

__global__ void bg_init(float* __restrict__ acc,
                        unsigned int* __restrict__ max_bits,
                        const int* __restrict__ num_pids_p) {
    const int P = *num_pids_p;
    const int gstride = gridDim.x * blockDim.x;
    const int tid = blockIdx.x * blockDim.x + threadIdx.x;
    if (tid < 4) acc[tid] = 0.0f;
    for (int i = tid; i < P; i += gstride) max_bits[i] = 0u;
}

__global__ void bg_main(const float* __restrict__ beta,
                        const int* __restrict__ pid,
                        float* __restrict__ acc,
                        unsigned int* __restrict__ max_bits, int n) {
    const int gstride = gridDim.x * blockDim.x;
    const int tid = blockIdx.x * blockDim.x + threadIdx.x;
    const int n4 = n >> 2;
    float noise_local = 0.0f;
    int nb_local = 0;
    auto proc = [&](int p, float b) {
        if (p == 0) { noise_local += b; nb_local += 1; }
        else {
            unsigned int bits = __float_as_uint(b) + 1u;
            if (bits > max_bits[p]) atomicMax(&max_bits[p], bits);
        }
    };
    const float4* __restrict__ b4 = (const float4*)beta;
    const int4* __restrict__ p4 = (const int4*)pid;
    for (int i = tid; i < n4; i += gstride) {
        float4 b = b4[i]; int4 p = p4[i];
        proc(p.x, b.x); proc(p.y, b.y); proc(p.z, b.z); proc(p.w, b.w);
    }
    for (int i = (n4 << 2) + tid; i < n; i += gstride)
        proc(pid[i], beta[i]);
    #pragma unroll
    for (int off = 32; off > 0; off >>= 1) {
        noise_local += __shfl_down(noise_local, off);
        nb_local    += __shfl_down(nb_local, off);
    }
    if ((threadIdx.x & 63) == 0 && nb_local != 0) {
        atomicAdd(&acc[ACC_NOISE], noise_local);
        atomicAdd(&acc[ACC_NB], (float)nb_local);
    }
}

__global__ void bg_reduce(const unsigned int* __restrict__ max_bits,
                          float* __restrict__ acc,
                          const int* __restrict__ num_pids_p) {
    const int P = *num_pids_p;
    const int gstride = gridDim.x * blockDim.x;
    float s = 0.0f;
    int c = 0;
    for (int i = blockIdx.x * blockDim.x + threadIdx.x; i < P; i += gstride) {
        if (i == 0) continue;
        unsigned int v = max_bits[i];
        if (v != 0u) { s += 1.0f - __uint_as_float(v - 1u); c += 1; }
    }
    #pragma unroll
    for (int off = 32; off > 0; off >>= 1) {
        s += __shfl_down(s, off);
        c += __shfl_down(c, off);
    }
    if ((threadIdx.x & 63) == 0 && (c != 0 || s != 0.0f)) {
        atomicAdd(&acc[ACC_ATTR], s);
        atomicAdd(&acc[ACC_NVALID], (float)c);
    }
}

// ---------------- finalize ----------------

__global__ void bg_finalize(const float* __restrict__ acc,
                            float* __restrict__ out) {
    float nb = acc[ACC_NB];
    float n_valid = fmaxf(acc[ACC_NVALID], 1.0f);
    float attractive = acc[ACC_ATTR] / n_valid;
    float noise = 0.1f * acc[ACC_NOISE] / fmaxf(nb, 1.0f);
    out[0] = (nb == 0.0f) ? 0.0f : (attractive + noise);
}

extern "C" void kernel_launch(void* const* d_in, const int* in_sizes, int n_in,
                              void* d_out, int out_size, void* d_ws, size_t ws_size,
                              hipStream_t stream) {
    // inputs: 0=w, 1=beta, 2=x, 3=y, 4=particle_id, 5=num_pids (device scalar)
    const float* beta = (const float*)d_in[1];
    const int* pid = (const int*)d_in[4];
    const int* num_pids_p = (const int*)d_in[5];
    const int n = in_sizes[1];

    float* acc = (float*)d_ws;
    float* out = (float*)d_out;

    // 32 MB of slabs in both slab paths
    const size_t slab_bytes = (size_t)NRANGE * BPR * RANGE * sizeof(unsigned int);

    if (ws_size >= 16 + slab_bytes) {
        unsigned int* slabs = (unsigned int*)((char*)d_ws + 16);

        // opt in to 128 KB dynamic LDS; host-side attr call, capture-safe.
        // If refused, take the proven 64 KB path.
        bool big = (hipFuncSetAttribute(
                        (const void*)bg_main_big,
                        hipFuncAttributeMaxDynamicSharedMemorySize,
                        RANGE_BIG * (int)sizeof(unsigned int)) == hipSuccess);

        bg_init_acc<<<1, 64, 0, stream>>>(acc);
        if (big) {
            bg_main_big<<<NRANGE_BIG * BPR, TPB_BIG,
                          RANGE_BIG * sizeof(unsigned int), stream>>>(
                beta, pid, acc, slabs, n);
            bg_reduce_slab_t<RANGE_BITS_BIG>
                <<<(NRANGE_BIG * RANGE_BIG) / 256, 256, 0, stream>>>(
                    slabs, acc, num_pids_p);
        } else {
            bg_main_lds<<<NRANGE * BPR, TPB, 0, stream>>>(beta, pid, acc, slabs, n);
            bg_reduce_slab_t<RANGE_BITS>
                <<<(NRANGE * RANGE) / 256, 256, 0, stream>>>(
                    slabs, acc, num_pids_p);
        }
        bg_finalize<<<1, 1, 0, stream>>>(acc, out);
    } else {
        unsigned int* max_bits = (unsigned int*)((char*)d_ws + 16);
        bg_init<<<512, 256, 0, stream>>>(acc, max_bits, num_pids_p);
        bg_main<<<2048, 256, 0, stream>>>(beta, pid, acc, max_bits, n);
        bg_reduce<<<512, 256, 0, stream>>>(max_bits, acc, num_pids_p);
        bg_finalize<<<1, 1, 0, stream>>>(acc, out);
    }
}